// Round 9
// baseline (247.858 us; speedup 1.0000x reference)
//
#include <hip/hip_runtime.h>

#define BATCH 512
#define NN    200
#define SIG1  0.73105857863f   // sigmoid(1)
#define SIG0  0.5f             // sigmoid(0)

// ---------------------------------------------------------------------------
// prep: blocks 0..156: Rs[n][m] = 0.5*(R[n][m]+R[m][n]) + (n==m)   (fp32)
//       block 157:     Wc = W0 @ (W1 @ (W2 @ pw))   [200][2] fp32
__global__ __launch_bounds__(256) void prep(
    const float* __restrict__ R,
    const float* __restrict__ W0, const float* __restrict__ W1,
    const float* __restrict__ W2, const float* __restrict__ pw,
    float* __restrict__ Rs, float* __restrict__ Wc) {
    const int blk = blockIdx.x;
    const int tid = threadIdx.x;
    if (blk < 157) {
        int idx = blk * 256 + tid;
        if (idx < NN * NN) {
            int n = idx / NN, m = idx - n * NN;
            Rs[idx] = 0.5f * (R[idx] + R[m * NN + n]) + (n == m ? 1.f : 0.f);
        }
    } else {
        __shared__ float t0[256], t1[256];
        float a0 = 0.f, a1 = 0.f;
#pragma unroll 16
        for (int c = 0; c < 256; ++c) {
            float w2 = W2[tid * 256 + c];
            a0 += w2 * pw[2 * c];
            a1 += w2 * pw[2 * c + 1];
        }
        t0[tid] = a0; t1[tid] = a1;
        __syncthreads();
        float b0 = 0.f, b1 = 0.f;
#pragma unroll 16
        for (int h = 0; h < 256; ++h) {
            float w1 = W1[tid * 256 + h];
            b0 += w1 * t0[h];
            b1 += w1 * t1[h];
        }
        __syncthreads();
        t0[tid] = b0; t1[tid] = b1;
        __syncthreads();
        if (tid < NN) {
            float c0 = 0.f, c1 = 0.f;
#pragma unroll 16
            for (int o = 0; o < 256; ++o) {
                float w0 = W0[tid * 256 + o];
                c0 += w0 * t0[o];
                c1 += w0 * t1[o];
            }
            Wc[tid * 2 + 0] = c0;
            Wc[tid * 2 + 1] = c1;
        }
    }
}

// ---------------------------------------------------------------------------
// stream_pass: ALL HBM traffic, no barriers, no LDS.
// blk <  512: adj scan for graph blk  -> bits (uint4) + u-partials (float4)
// blk >= 512: z[b][n][2] = feat_b @ Wc for graph blk-512 (wave-per-row-slice)
__global__ __launch_bounds__(512, 8) void stream_pass(
    const float* __restrict__ adj, const float* __restrict__ feat,
    const float* __restrict__ Rs, const float* __restrict__ Wc,
    float* __restrict__ up, uint* __restrict__ bitws, float* __restrict__ z) {
    const int blk = blockIdx.x;
    const int tid = threadIdx.x;
    if (blk < BATCH) {
        const int b = blk;
        const int c4 = tid & 63;
        const int q  = tid >> 6;                 // 0..7
        const int cc = (c4 < 50) ? c4 : 49;
        const int col0 = cc * 4;
        const int n0 = q * 25;
        const float* adjb = adj + (size_t)b * NN * NN;
        uint m0 = 0, m1 = 0, m2 = 0, m3 = 0;
        float4 acc = {0.f, 0.f, 0.f, 0.f};
#pragma unroll 5
        for (int j = 0; j < 25; ++j) {
            int n = n0 + j;
            float4 a = *(const float4*)(adjb + n * NN + col0);
            float4 r = *(const float4*)(Rs   + n * NN + col0);
            bool t;
            t = a.x > 0.5f; m0 |= (uint)t << j; acc.x += r.x * (t ? SIG1 : SIG0);
            t = a.y > 0.5f; m1 |= (uint)t << j; acc.y += r.y * (t ? SIG1 : SIG0);
            t = a.z > 0.5f; m2 |= (uint)t << j; acc.z += r.z * (t ? SIG1 : SIG0);
            t = a.w > 0.5f; m3 |= (uint)t << j; acc.w += r.w * (t ? SIG1 : SIG0);
        }
        if (c4 < 50) {
            *(float4*)(up + ((size_t)(b * 8 + q)) * NN + col0) = acc;
            uint4 mb; mb.x = m0; mb.y = m1; mb.z = m2; mb.w = m3;
            *(uint4*)(bitws + ((size_t)(b * 8 + q) * 50 + cc) * 4) = mb;
        }
    } else {
        const int b = blk - BATCH;
        const int w = tid >> 6, l = tid & 63;    // wave w: rows 25w..25w+24
        float4 wA = {0.f, 0.f, 0.f, 0.f}, wB = {0.f, 0.f, 0.f, 0.f};
        if (l < 50) {
            wA = *(const float4*)(Wc + 8 * l);       // (c0,c1) for f=4l,4l+1
            wB = *(const float4*)(Wc + 8 * l + 4);   // (c0,c1) for f=4l+2,4l+3
        }
        const float* fb = feat + (size_t)b * NN * NN;
#pragma unroll 5
        for (int k = 0; k < 25; ++k) {
            int n = w * 25 + k;
            float p0 = 0.f, p1 = 0.f;
            if (l < 50) {
                float4 f = *(const float4*)(fb + n * NN + 4 * l);
                p0 = f.x * wA.x + f.y * wA.z + f.z * wB.x + f.w * wB.z;
                p1 = f.x * wA.y + f.y * wA.w + f.z * wB.y + f.w * wB.w;
            }
#pragma unroll
            for (int off = 32; off > 0; off >>= 1) {
                p0 += __shfl_down(p0, off);
                p1 += __shfl_down(p1, off);
            }
            if (l == 0) {
                float2 zz; zz.x = p0; zz.y = p1;
                *(float2*)(z + ((size_t)b * NN + n) * 2) = zz;
            }
        }
    }
}

// ---------------------------------------------------------------------------
// solve2: all-L2 work. u = sum_q up ; v = M^T u ; w = M^T v ; out = w^T z / N + pb
__global__ __launch_bounds__(512, 8) void solve2(
    const float* __restrict__ Rs, const float* __restrict__ up,
    const uint* __restrict__ bitws, const float* __restrict__ z,
    const float* __restrict__ pb, float* __restrict__ out) {
    const int b = blockIdx.x;
    const int tid = threadIdx.x;
    const int c4 = tid & 63;
    const int q  = tid >> 6;
    const int cc = (c4 < 50) ? c4 : 49;
    const int col0 = cc * 4;
    const int n0 = q * 25;
    __shared__ float4 us[512];
    __shared__ float xs[NN];
    __shared__ float rbuf[16];

    uint4 mb = *(const uint4*)(bitws + ((size_t)(b * 8 + q) * 50 + cc) * 4);
    float4 zv = {0.f, 0.f, 0.f, 0.f};

    // u = sum over q of up partials
    us[tid] = (c4 < 50) ? *(const float4*)(up + ((size_t)(b * 8 + q)) * NN + col0) : zv;
    __syncthreads();
    if (tid < 64) {
        float4 s = us[tid];
#pragma unroll
        for (int qq = 1; qq < 8; ++qq) {
            float4 p = us[qq * 64 + tid];
            s.x += p.x; s.y += p.y; s.z += p.z; s.w += p.w;
        }
        if (tid < 50) {
            xs[tid * 4 + 0] = s.x; xs[tid * 4 + 1] = s.y;
            xs[tid * 4 + 2] = s.z; xs[tid * 4 + 3] = s.w;
        }
    }
    __syncthreads();

    // v = M^T u
    float4 acc = zv;
#pragma unroll 5
    for (int j = 0; j < 25; ++j) {
        int n = n0 + j;
        float4 r = *(const float4*)(Rs + n * NN + col0);
        float xn = xs[n];
        acc.x += r.x * (((mb.x >> j) & 1u) ? SIG1 : SIG0) * xn;
        acc.y += r.y * (((mb.y >> j) & 1u) ? SIG1 : SIG0) * xn;
        acc.z += r.z * (((mb.z >> j) & 1u) ? SIG1 : SIG0) * xn;
        acc.w += r.w * (((mb.w >> j) & 1u) ? SIG1 : SIG0) * xn;
    }
    us[tid] = acc;
    __syncthreads();
    if (tid < 64) {
        float4 s = us[tid];
#pragma unroll
        for (int qq = 1; qq < 8; ++qq) {
            float4 p = us[qq * 64 + tid];
            s.x += p.x; s.y += p.y; s.z += p.z; s.w += p.w;
        }
        if (tid < 50) {
            xs[tid * 4 + 0] = s.x; xs[tid * 4 + 1] = s.y;
            xs[tid * 4 + 2] = s.z; xs[tid * 4 + 3] = s.w;
        }
    }
    __syncthreads();

    // w = M^T v
    acc = zv;
#pragma unroll 5
    for (int j = 0; j < 25; ++j) {
        int n = n0 + j;
        float4 r = *(const float4*)(Rs + n * NN + col0);
        float xn = xs[n];
        acc.x += r.x * (((mb.x >> j) & 1u) ? SIG1 : SIG0) * xn;
        acc.y += r.y * (((mb.y >> j) & 1u) ? SIG1 : SIG0) * xn;
        acc.z += r.z * (((mb.z >> j) & 1u) ? SIG1 : SIG0) * xn;
        acc.w += r.w * (((mb.w >> j) & 1u) ? SIG1 : SIG0) * xn;
    }
    us[tid] = acc;
    __syncthreads();
    if (tid < 64) {
        float4 s = us[tid];
#pragma unroll
        for (int qq = 1; qq < 8; ++qq) {
            float4 p = us[qq * 64 + tid];
            s.x += p.x; s.y += p.y; s.z += p.z; s.w += p.w;
        }
        if (tid < 50) {
            xs[tid * 4 + 0] = s.x; xs[tid * 4 + 1] = s.y;
            xs[tid * 4 + 2] = s.z; xs[tid * 4 + 3] = s.w;
        }
    }
    __syncthreads();

    // out = (w^T z)/N + pb  (xs holds w)
    float p0 = 0.f, p1 = 0.f;
    if (tid < NN) {
        float2 zz = *(const float2*)(z + ((size_t)b * NN + tid) * 2);
        float wn = xs[tid];
        p0 = wn * zz.x; p1 = wn * zz.y;
    }
#pragma unroll
    for (int off = 32; off > 0; off >>= 1) {
        p0 += __shfl_down(p0, off);
        p1 += __shfl_down(p1, off);
    }
    const int wv = tid >> 6, ln = tid & 63;
    if (ln == 0) { rbuf[wv * 2] = p0; rbuf[wv * 2 + 1] = p1; }
    __syncthreads();
    if (tid == 0) {
        float r0 = 0.f, r1 = 0.f;
#pragma unroll
        for (int i = 0; i < 8; ++i) { r0 += rbuf[i * 2]; r1 += rbuf[i * 2 + 1]; }
        out[b * 2 + 0] = r0 * (1.f / NN) + pb[0];
        out[b * 2 + 1] = r1 * (1.f / NN) + pb[1];
    }
}

// ---------------------------------------------------------------------------
extern "C" void kernel_launch(void* const* d_in, const int* in_sizes, int n_in,
                              void* d_out, int out_size, void* d_ws, size_t ws_size,
                              hipStream_t stream) {
    const float* adj  = (const float*)d_in[0];
    const float* feat = (const float*)d_in[1];
    const float* R    = (const float*)d_in[2];
    const float* W0   = (const float*)d_in[3];
    const float* W1   = (const float*)d_in[4];
    const float* W2   = (const float*)d_in[5];
    const float* pw   = (const float*)d_in[6];
    const float* pb   = (const float*)d_in[7];

    char* ws = (char*)d_ws;
    float* Rs    = (float*)(ws);               // 160,000 B
    float* Wc    = (float*)(ws + 160000);      // 1,600 B
    float* up    = (float*)(ws + 163840);      // 512*8*200*4  = 3,276,800 B
    uint*  bitws = (uint*)(ws + 3440640);      // 512*8*50*16  = 3,276,800 B
    float* z     = (float*)(ws + 6717440);     // 512*200*2*4  =   819,200 B

    prep<<<158, 256, 0, stream>>>(R, W0, W1, W2, pw, Rs, Wc);
    stream_pass<<<1024, 512, 0, stream>>>(adj, feat, Rs, Wc, up, bitws, z);
    solve2<<<BATCH, 512, 0, stream>>>(Rs, up, bitws, z, pb, (float*)d_out);
}